// Round 15
// baseline (169.187 us; speedup 1.0000x reference)
//
#include <hip/hip_runtime.h>
#include <hip/hip_bf16.h>
#include <stdint.h>

typedef unsigned short u16;
typedef __bf16 v8bf __attribute__((ext_vector_type(8)));
typedef float  v4f  __attribute__((ext_vector_type(4)));

#define N_ROWS 8192
#define C_REAL 10000
#define C_PAD  10240   /* 80 * 128 */
#define D_DIM  512
#define BM 128
#define BN 128
#define BK2 32
#define NSTEP (D_DIM / BK2)   /* 16 */

/* LDS map (bytes): TWO 16KB step-slots (each: A 8KB = 128 rows x 64B
   swizzled, B 8KB @+8192), slot0 @0, slot1 @16384; tables f2s @32768,
   c2s @33280, labs @33792. Total 34304 => 4 blocks/CU, 16 waves.
   ONE barrier per step: {BARRIER; vmcnt(0) [stage(k), issued a full step
   ago -> near-free]; STAGE(k+1)->other slot; COMPUTE(k)}. Safe because a
   wave's ds_reads of slot(k-1) are register-consumed before it reaches
   the barrier, so post-barrier STAGE overwrite of that slot cannot race.
   Halves r14's barrier count (the residual serial cost: no resource is
   >41% busy, the chain is barrier crossings). */
#define SM_SLOT  16384
#define SM_BOFF  8192
#define SM_F2    32768
#define SM_C2    33280
#define SM_LAB   33792
#define SM_TOTAL 34304
static_assert(4 * SM_TOTAL <= 160 * 1024, "want 4 blocks/CU");

#define NPART 32   /* finalize stage-1 blocks */

#define BARRIER() do { asm volatile("" ::: "memory"); \
                       __builtin_amdgcn_s_barrier();  \
                       asm volatile("" ::: "memory"); } while (0)
#define MFMA(d, a, b) d = __builtin_amdgcn_mfma_f32_16x16x32_bf16(a, b, d, 0, 0, 0)
#define GLL(gp, lp) __builtin_amdgcn_global_load_lds( \
    (const __attribute__((address_space(1))) void*)(gp), \
    (__attribute__((address_space(3))) void*)(lp), 16, 0, 0)

__device__ __forceinline__ unsigned pack2bf(float a, float b) {
    unsigned short ua = __builtin_bit_cast(unsigned short, (__bf16)a);
    unsigned short ub = __builtin_bit_cast(unsigned short, (__bf16)b);
    return (unsigned)ua | ((unsigned)ub << 16);
}

// L2-normalize one row (one wave): bf16 row out + f32 sum-of-squares of the
// normalized row. Padding rows: bf16 zeros, o2 = 1e30 (exp(-5e30) = 0).
__device__ __forceinline__ void norm_row(
    const float* __restrict__ x, u16* __restrict__ ob, float* __restrict__ o2,
    int row, int nreal, int lane)
{
    uint2* orow = (uint2*)(ob + (size_t)row * D_DIM);
    if (row >= nreal) {
        uint2 z; z.x = 0u; z.y = 0u;
        orow[lane] = z; orow[64 + lane] = z;
        if (lane == 0) o2[row] = 1e30f;
        return;
    }
    const float4* xr = (const float4*)(x + (size_t)row * D_DIM);
    float4 v0 = xr[lane];
    float4 v1 = xr[64 + lane];
    float s = v0.x*v0.x + v0.y*v0.y + v0.z*v0.z + v0.w*v0.w
            + v1.x*v1.x + v1.y*v1.y + v1.z*v1.z + v1.w*v1.w;
    #pragma unroll
    for (int m = 1; m < 64; m <<= 1) s += __shfl_xor(s, m, 64);
    float inv = 1.0f / fmaxf(sqrtf(s), 1e-12f);
    if (lane == 0) o2[row] = s * inv * inv;
    uint2 p0, p1;
    p0.x = pack2bf(v0.x * inv, v0.y * inv);
    p0.y = pack2bf(v0.z * inv, v0.w * inv);
    p1.x = pack2bf(v1.x * inv, v1.y * inv);
    p1.y = pack2bf(v1.z * inv, v1.w * inv);
    orow[lane]      = p0;
    orow[64 + lane] = p1;
}

// Exact (f32) positive-class distance for one row (one wave).
__device__ __forceinline__ void pos_row(
    const float* __restrict__ feat, const float* __restrict__ cent,
    const int* __restrict__ labels, float* __restrict__ pose,
    int row, int lane)
{
    int lab = labels[row];
    const float4* fr = (const float4*)(feat + (size_t)row * D_DIM);
    const float4* cr = (const float4*)(cent + (size_t)lab * D_DIM);
    float sf = 0.f, sc = 0.f, sd = 0.f;
    #pragma unroll
    for (int i = 0; i < 2; ++i) {
        float4 a = fr[i * 64 + lane];
        float4 b = cr[i * 64 + lane];
        sf += a.x*a.x + a.y*a.y + a.z*a.z + a.w*a.w;
        sc += b.x*b.x + b.y*b.y + b.z*b.z + b.w*b.w;
        sd += a.x*b.x + a.y*b.y + a.z*b.z + a.w*b.w;
    }
    #pragma unroll
    for (int m = 1; m < 64; m <<= 1) {
        sf += __shfl_xor(sf, m, 64);
        sc += __shfl_xor(sc, m, 64);
        sd += __shfl_xor(sd, m, 64);
    }
    if (lane == 0) {
        float invf = 1.f / fmaxf(sqrtf(sf), 1e-12f);
        float invc = 1.f / fmaxf(sqrtf(sc), 1e-12f);
        pose[row] = -5.0f * (sf * invf * invf + sc * invc * invc
                             - 2.0f * sd * invf * invc);
    }
}

// Fused prep: one launch covers norm(features), norm(centers+pad), pos_exact.
__global__ __launch_bounds__(256) void prep_kernel(
    const float* __restrict__ features, const float* __restrict__ centers,
    const int* __restrict__ labels,
    u16* __restrict__ fb, u16* __restrict__ cb,
    float* __restrict__ f2, float* __restrict__ c2, float* __restrict__ pose)
{
    int b = blockIdx.x;
    int sub = threadIdx.x >> 6;
    int lane = threadIdx.x & 63;
    if (b < 2048) {
        norm_row(features, fb, f2, b * 4 + sub, N_ROWS, lane);
    } else if (b < 4608) {
        norm_row(centers, cb, c2, (b - 2048) * 4 + sub, C_REAL, lane);
    } else {
        pos_row(features, centers, labels, pose, (b - 4608) * 4 + sub, lane);
    }
}

// 128x128x(BK=32) 4-wave MFMA GEMM, double-buffered 16KB step-slots,
// 4 blocks/CU (16 waves), ONE barrier per K-step (see LDS-map comment).
// Swizzle for 64B rows: physical chunk = logical ^ ((row>>1)&3) —
// verified conflict-free in r14 (SQ_LDS_BANK_CONFLICT = 0).
// Grid (80,64): 80%8==0 => XCD = x%8 => per-XCD B-slice 1.3MB + window
// A ~1MB < 4MB L2 (measured FETCH 38MB). Fused exp epilogue.
__global__ __launch_bounds__(256, 4) void gemm_kernel(
    const u16* __restrict__ A, const u16* __restrict__ B,
    const float* __restrict__ f2, const float* __restrict__ c2,
    const int* __restrict__ labels,
    float* __restrict__ rowsum, float* __restrict__ posdis)
{
    extern __shared__ char sm[];
    const int rowBase = blockIdx.y * BM;
    const int colBase = blockIdx.x * BN;
    const int tid  = threadIdx.x;
    const int lane = tid & 63;
    const int w    = tid >> 6;      // 0..3
    const int wr   = w >> 1;        // 0..1 : 64-row group
    const int wc   = w & 1;         // 0..1 : 64-col group
    const int l15  = lane & 15;
    const int h4   = lane >> 4;

    // ---- staging geometry (r14-verified): per matrix sub-tile 128 rows x
    // 4 chunks(16B); thread covers chunks c = tid (r = tid>>2) and tid+256
    // (r+64); pc = tid&3, lc = pc ^ ((r>>1)&3), invariant under +64.
    const int r0  = tid >> 2;                       // 0..63
    const int lc0 = (tid & 3) ^ ((tid >> 3) & 3);   // (r0>>1)&3
    const size_t gOff = (size_t)r0 * D_DIM + lc0 * 8;   // elements
    const u16* aP = A + (size_t)rowBase * D_DIM + gOff; // +32768 elems for +64 rows
    const u16* bP = B + (size_t)colBase * D_DIM + gOff;
    const int d0 = tid * 16;                            // LDS bytes; +4096 for i=1

    #define STAGE4(SL, KOFS) do { \
        GLL(aP + (KOFS),         sm + (SL) + d0);                  \
        GLL(aP + (KOFS) + 32768, sm + (SL) + 4096 + d0);           \
        GLL(bP + (KOFS),         sm + (SL) + SM_BOFF + d0);        \
        GLL(bP + (KOFS) + 32768, sm + (SL) + SM_BOFF + 4096 + d0); \
    } while (0)

    // ---- fragment read bases (r14-verified): row = g*64 + m*16 + l15 =>
    // (row>>1)&3 = (l15>>1)&3 => swizzled byte col = (h4 ^ ((l15>>1)&3))*16.
    const int sw  = (h4 ^ ((l15 >> 1) & 3)) << 4;
    const int aO  = wr * 4096 + l15 * 64 + sw;
    const int bO  = SM_BOFF + wc * 4096 + l15 * 64 + sw;

    // ---- prologue: epilogue tables + step 0 into slot0; full drain once ----
    if (tid < 128) {
        ((float*)(sm + SM_F2))[tid] = f2[rowBase + tid];
        ((int*)(sm + SM_LAB))[tid]  = labels[rowBase + tid];
    } else {
        ((float*)(sm + SM_C2))[tid - 128] = c2[colBase + (tid - 128)];
    }
    STAGE4(0, 0);
    __syncthreads();

    v4f acc[4][4];
    #pragma unroll
    for (int m = 0; m < 4; ++m)
        #pragma unroll
        for (int n = 0; n < 4; ++n) acc[m][n] = (v4f){0.f, 0.f, 0.f, 0.f};

    // One barrier per step: {BARRIER; vmcnt(0) [stage(k) issued a full
    // step ago]; STAGE(k+1)->other slot; COMPUTE(k)}. The memory clobber
    // after STAGE pins GLL issue before the ds_reads (whose MFMA consumers
    // define the compute phase the stage hides under).
    #pragma unroll
    for (int k = 0; k < NSTEP; ++k) {
        const int slc = (k & 1) * SM_SLOT;          // compile-time per iter
        if (k) BARRIER();
        asm volatile("s_waitcnt vmcnt(0)" ::: "memory");
        if (k + 1 < NSTEP) {
            STAGE4(((k + 1) & 1) * SM_SLOT, (k + 1) * BK2);
            asm volatile("" ::: "memory");
        }

        v8bf a[4], b[4];
        #pragma unroll
        for (int m = 0; m < 4; ++m) a[m] = *(const v8bf*)(sm + slc + aO + m * 1024);
        #pragma unroll
        for (int n = 0; n < 4; ++n) b[n] = *(const v8bf*)(sm + slc + bO + n * 1024);
        __builtin_amdgcn_s_setprio(1);
        #pragma unroll
        for (int m = 0; m < 4; ++m)
            #pragma unroll
            for (int n = 0; n < 4; ++n)
                MFMA(acc[m][n], a[m], b[n]);
        __builtin_amdgcn_s_setprio(0);
    }
    #undef STAGE4

    // Epilogue: dis = -5*(f2 + c2 - 2*dot); exp; per-row sums; label capture.
    float* rs = rowsum + (size_t)(blockIdx.x & 7) * N_ROWS;  // per-XCD slice
    const float* f2s  = (const float*)(sm + SM_F2);
    const float* c2s  = (const float*)(sm + SM_C2);
    const int*   labs = (const int*)(sm + SM_LAB);
    #pragma unroll
    for (int m = 0; m < 4; ++m) {
        float s[4] = {0.f, 0.f, 0.f, 0.f};
        const int lr0 = wr * 64 + m * 16 + h4 * 4;
        #pragma unroll
        for (int n = 0; n < 4; ++n) {
            const int lcol = wc * 64 + n * 16 + l15;
            const int gcol = colBase + lcol;
            const float cc = c2s[lcol];
            #pragma unroll
            for (int j = 0; j < 4; ++j) {
                const int lr = lr0 + j;
                float dis = -5.0f * (f2s[lr] + cc - 2.0f * acc[m][n][j]);
                float e = __expf(dis);
                s[j] += e;
                if (labs[lr] == gcol) posdis[rowBase + lr] = dis;
            }
        }
        #pragma unroll
        for (int msk = 1; msk < 16; msk <<= 1) {
            #pragma unroll
            for (int j = 0; j < 4; ++j) s[j] += __shfl_xor(s[j], msk, 64);
        }
        if (l15 == 0) {
            #pragma unroll
            for (int j = 0; j < 4; ++j)
                atomicAdd(&rs[rowBase + lr0 + j], s[j]);
        }
    }
}

// Finalize stage 1: NPART blocks each reduce 256 rows -> f64 partial triple.
__global__ __launch_bounds__(256) void finalize_part_kernel(
    const float* __restrict__ posdis, const float* __restrict__ pose,
    const float* __restrict__ rowsum, const int* __restrict__ labels,
    const float* __restrict__ bias, double* __restrict__ partials)
{
    int t = threadIdx.x;
    int r = blockIdx.x * (N_ROWS / NPART) + t;
    float rsum = 0.f;
    #pragma unroll
    for (int x = 0; x < 8; ++x) rsum += rowsum[x * N_ROWS + r];
    float pd = posdis[r];                 // bf16-path label term (matches rowsum)
    float p  = pose[r] + bias[labels[r]]; // exact-path pos_metric
    float num = __expf(p);
    float den = rsum - __expf(pd) + num;
    double sl  = (double)(logf(den) - p);
    double sp  = (double)p;
    double sp2 = (double)p * (double)p;
    #pragma unroll
    for (int m = 1; m < 64; m <<= 1) {
        sl  += __shfl_xor(sl,  m, 64);
        sp  += __shfl_xor(sp,  m, 64);
        sp2 += __shfl_xor(sp2, m, 64);
    }
    __shared__ double sh[3][4];
    int w = t >> 6, lane = t & 63;
    if (lane == 0) { sh[0][w] = sl; sh[1][w] = sp; sh[2][w] = sp2; }
    __syncthreads();
    if (t == 0) {
        partials[blockIdx.x * 3 + 0] = sh[0][0] + sh[0][1] + sh[0][2] + sh[0][3];
        partials[blockIdx.x * 3 + 1] = sh[1][0] + sh[1][1] + sh[1][2] + sh[1][3];
        partials[blockIdx.x * 3 + 2] = sh[2][0] + sh[2][1] + sh[2][2] + sh[2][3];
    }
}

// Finalize stage 2: one wave combines NPART partials (deterministic order).
__global__ __launch_bounds__(64) void finalize_comb_kernel(
    const double* __restrict__ partials, float* __restrict__ out)
{
    int t = threadIdx.x;
    double sl = 0.0, sp = 0.0, sp2 = 0.0;
    if (t < NPART) {
        sl  = partials[t * 3 + 0];
        sp  = partials[t * 3 + 1];
        sp2 = partials[t * 3 + 2];
    }
    #pragma unroll
    for (int m = 1; m < 64; m <<= 1) {
        sl  += __shfl_xor(sl,  m, 64);
        sp  += __shfl_xor(sp,  m, 64);
        sp2 += __shfl_xor(sp2, m, 64);
    }
    if (t == 0) {
        const double N = (double)N_ROWS;
        double mean = sp / N;
        double var  = (sp2 - N * mean * mean) / (N - 1.0);
        out[0] = (float)(sl / N + var);
        out[1] = (float)var;
    }
}

extern "C" void kernel_launch(void* const* d_in, const int* in_sizes, int n_in,
                              void* d_out, int out_size, void* d_ws, size_t ws_size,
                              hipStream_t stream) {
    const float* features = (const float*)d_in[0];
    const int*   labels   = (const int*)d_in[1];
    const float* centers  = (const float*)d_in[2];
    const float* bias     = (const float*)d_in[3];
    float* out = (float*)d_out;
    char* ws = (char*)d_ws;

    // Workspace layout (16B aligned), ~19.3 MB total.
    u16*    fb     = (u16*)(ws);                 // 8192*512*2  = 8388608
    u16*    cb     = (u16*)(ws + 8388608);       // 10240*512*2 = 10485760
    float*  f2     = (float*)(ws + 18874368);    // 8192*4
    float*  c2     = (float*)(ws + 18907136);    // 10240*4
    float*  rowsum = (float*)(ws + 18948096);    // 8*8192*4 = 262144
    float*  posdis = (float*)(ws + 19210240);    // 8192*4
    float*  pose   = (float*)(ws + 19243008);    // 8192*4
    double* parts  = (double*)(ws + 19275776);   // 32*3*8 = 768

    hipMemsetAsync(rowsum, 0, 8 * N_ROWS * sizeof(float), stream);

    hipLaunchKernelGGL(prep_kernel, dim3(6656), dim3(256), 0, stream,
                       features, centers, labels, fb, cb, f2, c2, pose);

    hipFuncSetAttribute(reinterpret_cast<const void*>(gemm_kernel),
                        hipFuncAttributeMaxDynamicSharedMemorySize, SM_TOTAL);
    hipLaunchKernelGGL(gemm_kernel, dim3(C_PAD / BN, N_ROWS / BM), dim3(256), SM_TOTAL, stream,
                       fb, cb, f2, c2, labels, rowsum, posdis);

    hipLaunchKernelGGL(finalize_part_kernel, dim3(NPART), dim3(256), 0, stream,
                       posdis, pose, rowsum, labels, bias, parts);
    hipLaunchKernelGGL(finalize_comb_kernel, dim3(1), dim3(64), 0, stream,
                       parts, out);
}

// Round 16
// 165.095 us; speedup vs baseline: 1.0248x; 1.0248x over previous
//
#include <hip/hip_runtime.h>
#include <hip/hip_bf16.h>
#include <stdint.h>

typedef unsigned short u16;
typedef __bf16 v8bf __attribute__((ext_vector_type(8)));
typedef float  v4f  __attribute__((ext_vector_type(4)));

#define N_ROWS 8192
#define C_REAL 10000
#define C_PAD  10240   /* 40 * 256 */
#define D_DIM  512
#define BM 256
#define BN 256
#define BK 64
#define KTILES (D_DIM / BK)   /* 8 */

/* LDS (bytes): two 64KB K-tile buffers; within a buffer: A0 (rows 0-127)
   @0, A1 (rows 128-255) @16384, B0 @32768, B1 @49152 — each 128x64 bf16,
   XOR-8 swizzled (r2-verified, 0 conflicts). Tables: f2s @131072,
   c2s @132096, labs @133120. Total 134144 => 1 block/CU, 8 waves. */
#define SM_BUF   65536
#define SM_F2   131072
#define SM_C2   132096
#define SM_LAB  133120
#define SM_TOTAL 134144
static_assert(SM_TOTAL <= 160 * 1024, "LDS budget");

#define NPART 32   /* finalize stage-1 blocks */

#define BARRIER() do { asm volatile("" ::: "memory"); \
                       __builtin_amdgcn_s_barrier();  \
                       asm volatile("" ::: "memory"); } while (0)
#define LGKM0 asm volatile("s_waitcnt lgkmcnt(0)" ::: "memory")
#define MFMA(d, a, b) d = __builtin_amdgcn_mfma_f32_16x16x32_bf16(a, b, d, 0, 0, 0)
#define GLL(gp, lp) __builtin_amdgcn_global_load_lds( \
    (const __attribute__((address_space(1))) void*)(gp), \
    (__attribute__((address_space(3))) void*)(lp), 16, 0, 0)

__device__ __forceinline__ unsigned pack2bf(float a, float b) {
    unsigned short ua = __builtin_bit_cast(unsigned short, (__bf16)a);
    unsigned short ub = __builtin_bit_cast(unsigned short, (__bf16)b);
    return (unsigned)ua | ((unsigned)ub << 16);
}

// L2-normalize one row (one wave): bf16 row out + f32 sum-of-squares of the
// normalized row. Padding rows: bf16 zeros, o2 = 1e30 (exp(-5e30) = 0).
__device__ __forceinline__ void norm_row(
    const float* __restrict__ x, u16* __restrict__ ob, float* __restrict__ o2,
    int row, int nreal, int lane)
{
    uint2* orow = (uint2*)(ob + (size_t)row * D_DIM);
    if (row >= nreal) {
        uint2 z; z.x = 0u; z.y = 0u;
        orow[lane] = z; orow[64 + lane] = z;
        if (lane == 0) o2[row] = 1e30f;
        return;
    }
    const float4* xr = (const float4*)(x + (size_t)row * D_DIM);
    float4 v0 = xr[lane];
    float4 v1 = xr[64 + lane];
    float s = v0.x*v0.x + v0.y*v0.y + v0.z*v0.z + v0.w*v0.w
            + v1.x*v1.x + v1.y*v1.y + v1.z*v1.z + v1.w*v1.w;
    #pragma unroll
    for (int m = 1; m < 64; m <<= 1) s += __shfl_xor(s, m, 64);
    float inv = 1.0f / fmaxf(sqrtf(s), 1e-12f);
    if (lane == 0) o2[row] = s * inv * inv;
    uint2 p0, p1;
    p0.x = pack2bf(v0.x * inv, v0.y * inv);
    p0.y = pack2bf(v0.z * inv, v0.w * inv);
    p1.x = pack2bf(v1.x * inv, v1.y * inv);
    p1.y = pack2bf(v1.z * inv, v1.w * inv);
    orow[lane]      = p0;
    orow[64 + lane] = p1;
}

// Exact (f32) positive-class distance for one row (one wave).
__device__ __forceinline__ void pos_row(
    const float* __restrict__ feat, const float* __restrict__ cent,
    const int* __restrict__ labels, float* __restrict__ pose,
    int row, int lane)
{
    int lab = labels[row];
    const float4* fr = (const float4*)(feat + (size_t)row * D_DIM);
    const float4* cr = (const float4*)(cent + (size_t)lab * D_DIM);
    float sf = 0.f, sc = 0.f, sd = 0.f;
    #pragma unroll
    for (int i = 0; i < 2; ++i) {
        float4 a = fr[i * 64 + lane];
        float4 b = cr[i * 64 + lane];
        sf += a.x*a.x + a.y*a.y + a.z*a.z + a.w*a.w;
        sc += b.x*b.x + b.y*b.y + b.z*b.z + b.w*b.w;
        sd += a.x*b.x + a.y*b.y + a.z*b.z + a.w*b.w;
    }
    #pragma unroll
    for (int m = 1; m < 64; m <<= 1) {
        sf += __shfl_xor(sf, m, 64);
        sc += __shfl_xor(sc, m, 64);
        sd += __shfl_xor(sd, m, 64);
    }
    if (lane == 0) {
        float invf = 1.f / fmaxf(sqrtf(sf), 1e-12f);
        float invc = 1.f / fmaxf(sqrtf(sc), 1e-12f);
        pose[row] = -5.0f * (sf * invf * invf + sc * invc * invc
                             - 2.0f * sd * invf * invc);
    }
}

// Fused prep: one launch covers norm(features), norm(centers+pad), pos_exact.
__global__ __launch_bounds__(256) void prep_kernel(
    const float* __restrict__ features, const float* __restrict__ centers,
    const int* __restrict__ labels,
    u16* __restrict__ fb, u16* __restrict__ cb,
    float* __restrict__ f2, float* __restrict__ c2, float* __restrict__ pose)
{
    int b = blockIdx.x;
    int sub = threadIdx.x >> 6;
    int lane = threadIdx.x & 63;
    if (b < 2048) {
        norm_row(features, fb, f2, b * 4 + sub, N_ROWS, lane);
    } else if (b < 4608) {
        norm_row(centers, cb, c2, (b - 2048) * 4 + sub, C_REAL, lane);
    } else {
        pos_row(features, centers, labels, pose, (b - 4608) * 4 + sub, lane);
    }
}

// 256x256x(BK=64) 8-wave MFMA GEMM — faithful m201 8-phase schedule:
// per phase {ds_read quadrant subtile; stage ONE half-tile (2 GLL) into a
// region already retired (B regions retire after ph2, A after ph3, with
// barriers between); barrier; lgkmcnt(0); setprio(1); 16 MFMA; setprio(0);
// barrier}. Counted vmcnt(4) ONLY at phases 4/8 — verified by load-order
// count: at each wait the next K-tile's 8 loads are landed, 4 newest stay
// in flight (never a drain until the tail). Stage schedule per iteration i
// (tiles 2i in buf0, 2i+1 in buf1): ph1 A0(2i+1), ph2 A1(2i+1),
// ph3 B0(2i+2), ph4 B1(2i+2), ph5 A0(2i+2), ph6 A1(2i+2), ph7 B0(2i+3),
// ph8 B1(2i+3). XOR-8 swizzle + fragment addressing byte-identical to r2
// (refchecked, 0 bank conflicts). Grid (40,32): XCD = x%8 (B-slice 1.3MB
// L2-resident). Fused exp epilogue; rowsum per-XCD slices.
__global__ __launch_bounds__(512, 2) void gemm_kernel(
    const u16* __restrict__ A, const u16* __restrict__ B,
    const float* __restrict__ f2, const float* __restrict__ c2,
    const int* __restrict__ labels,
    float* __restrict__ rowsum, float* __restrict__ posdis)
{
    extern __shared__ char sm[];
    const int rowBase = blockIdx.y * BM;
    const int colBase = blockIdx.x * BN;
    const int tid  = threadIdx.x;
    const int lane = tid & 63;
    const int w    = tid >> 6;      // 0..7
    const int wr   = w >> 2;        // 0..1 : 128-row group
    const int wc   = w & 3;         // 0..3 : 64-col group
    const int l15  = lane & 15;
    const int h4   = lane >> 4;

    // ---- staging geometry (r2-verified): half = 128 rows x 64 cols;
    // chunk c = tid (+512): r = tid>>3 (+64), pc = tid&7, lc = pc ^ (r&7).
    const int r0  = tid >> 3;
    const int lc0 = (tid & 7) ^ (r0 & 7);
    const size_t gOff = (size_t)r0 * D_DIM + lc0 * 8;   // elements
    const u16* pA0 = A + (size_t)rowBase * D_DIM + gOff;
    const u16* pA1 = pA0 + (size_t)128 * D_DIM;
    const u16* pB0 = B + (size_t)colBase * D_DIM + gOff;
    const u16* pB1 = pB0 + (size_t)128 * D_DIM;
    const int dA = tid * 16;

    auto stA0 = [&](int buf, int kt) {
        GLL(pA0 + kt * 64,                       sm + buf + dA);
        GLL(pA0 + kt * 64 + (size_t)64 * D_DIM,  sm + buf + 8192 + dA);
    };
    auto stA1 = [&](int buf, int kt) {
        GLL(pA1 + kt * 64,                       sm + buf + 16384 + dA);
        GLL(pA1 + kt * 64 + (size_t)64 * D_DIM,  sm + buf + 16384 + 8192 + dA);
    };
    auto stB0 = [&](int buf, int kt) {
        GLL(pB0 + kt * 64,                       sm + buf + 32768 + dA);
        GLL(pB0 + kt * 64 + (size_t)64 * D_DIM,  sm + buf + 32768 + 8192 + dA);
    };
    auto stB1 = [&](int buf, int kt) {
        GLL(pB1 + kt * 64,                       sm + buf + 49152 + dA);
        GLL(pB1 + kt * 64 + (size_t)64 * D_DIM,  sm + buf + 49152 + 8192 + dA);
    };

    // ---- fragment read bases (r2-verified): row&7 == l15&7 =>
    // swizzled byte col = ((ks*4+h4) ^ (l15&7)) * 16.
    const int s0 = ((h4)     ^ (l15 & 7)) << 4;
    const int s1 = ((4 + h4) ^ (l15 & 7)) << 4;
    const int aBase = wr * 16384 + l15 * 128;                         // + mh*8192 + m*2048
    const int bBase = 32768 + (wc >> 1) * 16384 + (wc & 1) * 8192 + l15 * 128;  // + n*2048

    v8bf aF[4][2], bFa[2][2], bFb[2][2];
    v4f acc[8][4];
    #pragma unroll
    for (int m = 0; m < 8; ++m)
        #pragma unroll
        for (int n = 0; n < 4; ++n) acc[m][n] = (v4f){0.f, 0.f, 0.f, 0.f};

    auto rdA = [&](int buf, int mh) {
        #pragma unroll
        for (int m = 0; m < 4; ++m) {
            aF[m][0] = *(const v8bf*)(sm + buf + aBase + mh * 8192 + m * 2048 + s0);
            aF[m][1] = *(const v8bf*)(sm + buf + aBase + mh * 8192 + m * 2048 + s1);
        }
    };
    auto rdB = [&](int buf, v8bf (&bf)[2][2], int no) {
        #pragma unroll
        for (int n = 0; n < 2; ++n) {
            bf[n][0] = *(const v8bf*)(sm + buf + bBase + (no + n) * 2048 + s0);
            bf[n][1] = *(const v8bf*)(sm + buf + bBase + (no + n) * 2048 + s1);
        }
    };
    auto quad = [&](int mo, v8bf (&bf)[2][2], int no) {
        __builtin_amdgcn_s_setprio(1);
        #pragma unroll
        for (int m = 0; m < 4; ++m)
            #pragma unroll
            for (int n = 0; n < 2; ++n) {
                MFMA(acc[m + mo][n + no], aF[m][0], bf[n][0]);
                MFMA(acc[m + mo][n + no], aF[m][1], bf[n][1]);
            }
        __builtin_amdgcn_s_setprio(0);
    };

    // ---- prologue: tables + tile0 (buf0, 4 half-tiles) + tile1's B (buf1).
    if (tid < 256) {
        ((float*)(sm + SM_F2))[tid] = f2[rowBase + tid];
        ((int*)(sm + SM_LAB))[tid]  = labels[rowBase + tid];
    } else {
        ((float*)(sm + SM_C2))[tid - 256] = c2[colBase + (tid - 256)];
    }
    stA0(0, 0); stA1(0, 0); stB0(0, 0); stB1(0, 0);
    stB0(SM_BUF, 1); stB1(SM_BUF, 1);
    asm volatile("s_waitcnt vmcnt(4) lgkmcnt(0)" ::: "memory");
    BARRIER();

    // ---- main loop: 4 iterations x 8 phases; tiles 2i (buf0) & 2i+1 (buf1).
    #define ITER(KA, KB, KC, DOB, DOC) do {                                   \
        /* ph1: buf0 q(mh0,n01); stage A0(KA)->buf1 */                        \
        rdA(0, 0); rdB(0, bFa, 0); stA0(SM_BUF, KA);                          \
        BARRIER(); LGKM0; quad(0, bFa, 0); BARRIER();                         \
        /* ph2: buf0 q(mh0,n23); stage A1(KA)->buf1 */                        \
        rdB(0, bFb, 2); stA1(SM_BUF, KA);                                     \
        BARRIER(); LGKM0; quad(0, bFb, 2); BARRIER();                         \
        /* ph3: buf0 q(mh1,n23); stage B0(KB)->buf0 (B retired at ph2) */     \
        rdA(0, 1); if (DOB) stB0(0, KB);                                      \
        BARRIER(); LGKM0; quad(4, bFb, 2); BARRIER();                         \
        /* ph4: buf0 q(mh1,n01); stage B1(KB)->buf0; counted wait */          \
        if (DOB) { stB1(0, KB); asm volatile("s_waitcnt vmcnt(4)":::"memory");\
        } else   { asm volatile("s_waitcnt vmcnt(0)" ::: "memory"); }         \
        BARRIER(); quad(4, bFa, 0); BARRIER();                                \
        /* ph5: buf1 q(mh0,n01); stage A0(KB)->buf0 (A retired at ph3) */     \
        rdA(SM_BUF, 0); rdB(SM_BUF, bFa, 0); if (DOB) stA0(0, KB);            \
        BARRIER(); LGKM0; quad(0, bFa, 0); BARRIER();                         \
        /* ph6: buf1 q(mh0,n23); stage A1(KB)->buf0 */                        \
        rdB(SM_BUF, bFb, 2); if (DOB) stA1(0, KB);                            \
        BARRIER(); LGKM0; quad(0, bFb, 2); BARRIER();                         \
        /* ph7: buf1 q(mh1,n23); stage B0(KC)->buf1 (B retired at ph6) */     \
        rdA(SM_BUF, 1); if (DOC) stB0(SM_BUF, KC);                            \
        BARRIER(); LGKM0; quad(4, bFb, 2); BARRIER();                         \
        /* ph8: buf1 q(mh1,n01); stage B1(KC)->buf1; counted wait */          \
        if (DOC) { stB1(SM_BUF, KC);                                          \
                   asm volatile("s_waitcnt vmcnt(4)" ::: "memory"); }         \
        BARRIER(); quad(4, bFa, 0); BARRIER();                                \
    } while (0)

    ITER(1, 2, 3, 1, 1);
    ITER(3, 4, 5, 1, 1);
    ITER(5, 6, 7, 1, 1);
    ITER(7, 8, 9, 0, 0);
    #undef ITER

    // Epilogue (r2-verified indices): dis = -5*(f2 + c2 - 2*dot); exp;
    // per-row sums; label capture. rowsum split per-XCD (x%8).
    float* rs = rowsum + (size_t)(blockIdx.x & 7) * N_ROWS;
    const float* f2s  = (const float*)(sm + SM_F2);
    const float* c2s  = (const float*)(sm + SM_C2);
    const int*   labs = (const int*)(sm + SM_LAB);
    #pragma unroll
    for (int m = 0; m < 8; ++m) {
        float s[4] = {0.f, 0.f, 0.f, 0.f};
        const int lr0 = wr * 128 + m * 16 + h4 * 4;
        #pragma unroll
        for (int n = 0; n < 4; ++n) {
            const int lcol = wc * 64 + n * 16 + l15;
            const int gcol = colBase + lcol;
            const float cc = c2s[lcol];
            #pragma unroll
            for (int j = 0; j < 4; ++j) {
                const int lr = lr0 + j;
                float dis = -5.0f * (f2s[lr] + cc - 2.0f * acc[m][n][j]);
                float e = __expf(dis);
                s[j] += e;
                if (labs[lr] == gcol) posdis[rowBase + lr] = dis;
            }
        }
        #pragma unroll
        for (int msk = 1; msk < 16; msk <<= 1) {
            #pragma unroll
            for (int j = 0; j < 4; ++j) s[j] += __shfl_xor(s[j], msk, 64);
        }
        if (l15 == 0) {
            #pragma unroll
            for (int j = 0; j < 4; ++j)
                atomicAdd(&rs[rowBase + lr0 + j], s[j]);
        }
    }
}

// Finalize stage 1: NPART blocks each reduce 256 rows -> f64 partial triple.
__global__ __launch_bounds__(256) void finalize_part_kernel(
    const float* __restrict__ posdis, const float* __restrict__ pose,
    const float* __restrict__ rowsum, const int* __restrict__ labels,
    const float* __restrict__ bias, double* __restrict__ partials)
{
    int t = threadIdx.x;
    int r = blockIdx.x * (N_ROWS / NPART) + t;
    float rsum = 0.f;
    #pragma unroll
    for (int x = 0; x < 8; ++x) rsum += rowsum[x * N_ROWS + r];
    float pd = posdis[r];                 // bf16-path label term (matches rowsum)
    float p  = pose[r] + bias[labels[r]]; // exact-path pos_metric
    float num = __expf(p);
    float den = rsum - __expf(pd) + num;
    double sl  = (double)(logf(den) - p);
    double sp  = (double)p;
    double sp2 = (double)p * (double)p;
    #pragma unroll
    for (int m = 1; m < 64; m <<= 1) {
        sl  += __shfl_xor(sl,  m, 64);
        sp  += __shfl_xor(sp,  m, 64);
        sp2 += __shfl_xor(sp2, m, 64);
    }
    __shared__ double sh[3][4];
    int wv = t >> 6, lane = t & 63;
    if (lane == 0) { sh[0][wv] = sl; sh[1][wv] = sp; sh[2][wv] = sp2; }
    __syncthreads();
    if (t == 0) {
        partials[blockIdx.x * 3 + 0] = sh[0][0] + sh[0][1] + sh[0][2] + sh[0][3];
        partials[blockIdx.x * 3 + 1] = sh[1][0] + sh[1][1] + sh[1][2] + sh[1][3];
        partials[blockIdx.x * 3 + 2] = sh[2][0] + sh[2][1] + sh[2][2] + sh[2][3];
    }
}

// Finalize stage 2: one wave combines NPART partials (deterministic order).
__global__ __launch_bounds__(64) void finalize_comb_kernel(
    const double* __restrict__ partials, float* __restrict__ out)
{
    int t = threadIdx.x;
    double sl = 0.0, sp = 0.0, sp2 = 0.0;
    if (t < NPART) {
        sl  = partials[t * 3 + 0];
        sp  = partials[t * 3 + 1];
        sp2 = partials[t * 3 + 2];
    }
    #pragma unroll
    for (int m = 1; m < 64; m <<= 1) {
        sl  += __shfl_xor(sl,  m, 64);
        sp  += __shfl_xor(sp,  m, 64);
        sp2 += __shfl_xor(sp2, m, 64);
    }
    if (t == 0) {
        const double N = (double)N_ROWS;
        double mean = sp / N;
        double var  = (sp2 - N * mean * mean) / (N - 1.0);
        out[0] = (float)(sl / N + var);
        out[1] = (float)var;
    }
}

extern "C" void kernel_launch(void* const* d_in, const int* in_sizes, int n_in,
                              void* d_out, int out_size, void* d_ws, size_t ws_size,
                              hipStream_t stream) {
    const float* features = (const float*)d_in[0];
    const int*   labels   = (const int*)d_in[1];
    const float* centers  = (const float*)d_in[2];
    const float* bias     = (const float*)d_in[3];
    float* out = (float*)d_out;
    char* ws = (char*)d_ws;

    // Workspace layout (16B aligned), ~19.3 MB total.
    u16*    fb     = (u16*)(ws);                 // 8192*512*2  = 8388608
    u16*    cb     = (u16*)(ws + 8388608);       // 10240*512*2 = 10485760
    float*  f2     = (float*)(ws + 18874368);    // 8192*4
    float*  c2     = (float*)(ws + 18907136);    // 10240*4
    float*  rowsum = (float*)(ws + 18948096);    // 8*8192*4 = 262144
    float*  posdis = (float*)(ws + 19210240);    // 8192*4
    float*  pose   = (float*)(ws + 19243008);    // 8192*4
    double* parts  = (double*)(ws + 19275776);   // 32*3*8 = 768

    hipMemsetAsync(rowsum, 0, 8 * N_ROWS * sizeof(float), stream);

    hipLaunchKernelGGL(prep_kernel, dim3(6656), dim3(256), 0, stream,
                       features, centers, labels, fb, cb, f2, c2, pose);

    hipFuncSetAttribute(reinterpret_cast<const void*>(gemm_kernel),
                        hipFuncAttributeMaxDynamicSharedMemorySize, SM_TOTAL);
    hipLaunchKernelGGL(gemm_kernel, dim3(C_PAD / BN, N_ROWS / BM), dim3(512), SM_TOTAL, stream,
                       fb, cb, f2, c2, labels, rowsum, posdis);

    hipLaunchKernelGGL(finalize_part_kernel, dim3(NPART), dim3(256), 0, stream,
                       posdis, pose, rowsum, labels, bias, parts);
    hipLaunchKernelGGL(finalize_comb_kernel, dim3(1), dim3(64), 0, stream,
                       parts, out);
}